// Round 6
// baseline (196.124 us; speedup 1.0000x reference)
//
#include <hip/hip_runtime.h>
#include <math.h>

typedef __attribute__((ext_vector_type(8))) short bf8v;
typedef __attribute__((ext_vector_type(4))) float f4v;

union BF8 { bf8v v; unsigned short e[8]; };

__device__ __forceinline__ float bf2f(unsigned short u) {
  union { unsigned int i; float f; } c; c.i = ((unsigned int)u) << 16; return c.f;
}
__device__ __forceinline__ unsigned short f2bf(float f) {
  union { float f; unsigned int i; } c; c.f = f;
  return (unsigned short)((c.i + 0x7fffu + ((c.i >> 16) & 1u)) >> 16);
}
// global -> LDS direct DMA, 16B/lane; LDS dest = wave-uniform base + lane*16
__device__ __forceinline__ void gld16(const unsigned short* g, unsigned short* l) {
  __builtin_amdgcn_global_load_lds(
      (const __attribute__((address_space(1))) unsigned int*)g,
      (__attribute__((address_space(3))) unsigned int*)l, 16, 0, 0);
}

// ---------------- fused prelude + LayerNorm/transpose ----------------
// blk<2048: FiLM; <2560: wcvt; <3072: per-d tables; else LN+transpose (16 rows)
__global__ __launch_bounds__(256) void prelude_kernel(
    const float* __restrict__ emb, const float* __restrict__ Wf,
    const float* __restrict__ bfm, float* __restrict__ film,
    const float* __restrict__ W, unsigned short* __restrict__ Wb,
    const float* __restrict__ A_real, const float* __restrict__ A_imag,
    const float* __restrict__ Cc, const float* __restrict__ log_dt,
    const float* __restrict__ B_ssm, const float* __restrict__ D_skip,
    unsigned short* __restrict__ Pre, unsigned short* __restrict__ Pim,
    unsigned short* __restrict__ Mre, unsigned short* __restrict__ Mim,
    unsigned short* __restrict__ Tt, float* __restrict__ W64r, float* __restrict__ W64i,
    const float* __restrict__ x, const float* __restrict__ gamma,
    const float* __restrict__ beta, unsigned short* __restrict__ xT) {
  __shared__ __align__(16) char sh[16 * 520 * 2];
  const int blk = blockIdx.x;
  const int tid = threadIdx.x;
  if (blk < 2048) {            // ---- FiLM
    const int gw = blk * 4 + (tid >> 6);
    const int lane = tid & 63;
    const int b = gw >> 10, j = gw & 1023;
    const float4* ep = (const float4*)(emb + (size_t)b * 512) + lane * 2;
    const float4* wp = (const float4*)(Wf + (size_t)j * 512) + lane * 2;
    float acc = 0.f;
    #pragma unroll
    for (int i = 0; i < 2; i++) {
      const float4 e = ep[i], w = wp[i];
      acc += (e.x / (1.f + __expf(-e.x))) * w.x;
      acc += (e.y / (1.f + __expf(-e.y))) * w.y;
      acc += (e.z / (1.f + __expf(-e.z))) * w.z;
      acc += (e.w / (1.f + __expf(-e.w))) * w.w;
    }
    #pragma unroll
    for (int off = 32; off >= 1; off >>= 1) acc += __shfl_xor(acc, off);
    if (lane == 0) film[(size_t)b * 1024 + j] = acc + bfm[j];
  } else if (blk < 2560) {     // ---- W_out fp32 -> bf16
    const int i = (blk - 2048) * 256 + tid;
    const float4 v = ((const float4*)W)[i];
    uint2 pk;
    pk.x = (unsigned)f2bf(v.x) | ((unsigned)f2bf(v.y) << 16);
    pk.y = (unsigned)f2bf(v.z) | ((unsigned)f2bf(v.w) << 16);
    ((uint2*)Wb)[i] = pk;
  } else if (blk < 3072) {     // ---- tables for d
    float* Ktl = (float*)sh;
    const int d = blk - 2560;
    const float dt = __expf(log_dt[d]);
    const int wv = tid >> 6, n = tid & 63;
    {  // K[tau] = Re(sum_n cdt_n w_n^tau) (+D_skip at tau=0)
      const int dn = d * 64 + n;
      const float ar = dt * A_real[dn], ai = dt * A_imag[dn];
      const float bs = B_ssm[dn] * dt;
      const float c0 = Cc[dn * 2] * bs, c1 = Cc[dn * 2 + 1] * bs;
      #pragma unroll
      for (int i = 0; i < 16; i++) {
        const float tau = (float)(wv * 16 + i);
        const float ex = __expf(ar * tau);
        float sn, cs; __sincosf(ai * tau, &sn, &cs);
        float r = ex * (c0 * cs - c1 * sn);
        #pragma unroll
        for (int off = 32; off >= 1; off >>= 1) r += __shfl_xor(r, off);
        if (n == 0) Ktl[wv * 16 + i] = (wv * 16 + i == 0) ? (r + D_skip[d]) : r;
      }
    }
    __syncthreads();
    // P[n][s] = w_n^(63-s)
    for (int g = tid; g < 512; g += 256) {
      const int nn = g >> 3, s0 = (g & 7) * 8;
      const int dn = d * 64 + nn;
      const float ar = dt * A_real[dn], ai = dt * A_imag[dn];
      union { unsigned short s[8]; uint4 u; } pr, pi;
      #pragma unroll
      for (int j = 0; j < 8; j++) {
        const float k = (float)(63 - (s0 + j));
        const float ex = __expf(ar * k);
        float sn, cs; __sincosf(ai * k, &sn, &cs);
        pr.s[j] = f2bf(ex * cs); pi.s[j] = f2bf(ex * sn);
      }
      *(uint4*)(Pre + (size_t)d * 4096 + nn * 64 + s0) = pr.u;
      *(uint4*)(Pim + (size_t)d * 4096 + nn * 64 + s0) = pi.u;
    }
    // M[t][n]: re = Re(cdt_n w_n^(t+1)), im = -Im(...)
    for (int g = tid; g < 512; g += 256) {
      const int t = g >> 3, n0 = (g & 7) * 8;
      union { unsigned short s[8]; uint4 u; } mr, mi;
      #pragma unroll
      for (int j = 0; j < 8; j++) {
        const int dn = d * 64 + n0 + j;
        const float ar = dt * A_real[dn], ai = dt * A_imag[dn];
        const float bs = B_ssm[dn] * dt;
        const float c0 = Cc[dn * 2] * bs, c1 = Cc[dn * 2 + 1] * bs;
        const float k = (float)(t + 1);
        const float ex = __expf(ar * k);
        float sn, cs; __sincosf(ai * k, &sn, &cs);
        mr.s[j] = f2bf(ex * (c0 * cs - c1 * sn));
        mi.s[j] = f2bf(-ex * (c0 * sn + c1 * cs));
      }
      *(uint4*)(Mre + (size_t)d * 4096 + t * 64 + n0) = mr.u;
      *(uint4*)(Mim + (size_t)d * 4096 + t * 64 + n0) = mi.u;
    }
    // T[t][s] = K[t-s] for s<=t
    for (int g = tid; g < 512; g += 256) {
      const int t = g >> 3, s0 = (g & 7) * 8;
      union { unsigned short s[8]; uint4 u; } tv;
      #pragma unroll
      for (int j = 0; j < 8; j++) {
        const int s = s0 + j;
        tv.s[j] = (s <= t) ? f2bf(Ktl[t - s]) : (unsigned short)0;
      }
      *(uint4*)(Tt + (size_t)d * 4096 + t * 64 + s0) = tv.u;
    }
    if (tid < 64) {
      const int dn = d * 64 + tid;
      const float ex = __expf(dt * A_real[dn] * 64.f);
      float sn, cs; __sincosf(dt * A_imag[dn] * 64.f, &sn, &cs);
      W64r[d * 64 + tid] = ex * cs;
      W64i[d * 64 + tid] = ex * sn;
    }
  } else {                     // ---- LayerNorm + transpose, rows r0..r0+15
    unsigned short* t = (unsigned short*)sh;
    const int r0 = (blk - 3072) * 16;
    const int wv = tid >> 6, lane = tid & 63;
    const float4* gp = (const float4*)gamma + lane * 2;
    const float4* bp = (const float4*)beta  + lane * 2;
    const float4 g0 = gp[0], g1 = gp[1], bb0 = bp[0], bb1 = bp[1];
    #pragma unroll
    for (int i = 0; i < 4; i++) {
      const int r = wv * 4 + i;
      const float4* xr = (const float4*)(x + (size_t)(r0 + r) * 512) + lane * 2;
      const float4 v0 = xr[0], v1 = xr[1];
      float s  = v0.x + v0.y + v0.z + v0.w + v1.x + v1.y + v1.z + v1.w;
      float sq = v0.x*v0.x + v0.y*v0.y + v0.z*v0.z + v0.w*v0.w
               + v1.x*v1.x + v1.y*v1.y + v1.z*v1.z + v1.w*v1.w;
      #pragma unroll
      for (int off = 32; off >= 1; off >>= 1) {
        s  += __shfl_xor(s, off);
        sq += __shfl_xor(sq, off);
      }
      const float mu   = s * (1.f / 512.f);
      const float var  = sq * (1.f / 512.f) - mu * mu;
      const float rstd = rsqrtf(var + 1e-5f);
      uint4 pk;
      pk.x = (unsigned)f2bf((v0.x - mu) * rstd * g0.x + bb0.x)
           | ((unsigned)f2bf((v0.y - mu) * rstd * g0.y + bb0.y) << 16);
      pk.y = (unsigned)f2bf((v0.z - mu) * rstd * g0.z + bb0.z)
           | ((unsigned)f2bf((v0.w - mu) * rstd * g0.w + bb0.w) << 16);
      pk.z = (unsigned)f2bf((v1.x - mu) * rstd * g1.x + bb1.x)
           | ((unsigned)f2bf((v1.y - mu) * rstd * g1.y + bb1.y) << 16);
      pk.w = (unsigned)f2bf((v1.z - mu) * rstd * g1.z + bb1.z)
           | ((unsigned)f2bf((v1.w - mu) * rstd * g1.w + bb1.w) << 16);
      *(uint4*)&t[r * 520 + lane * 8] = pk;
    }
    __syncthreads();
    const int p = tid;
    union { unsigned short s[8]; uint4 u; } a0, a1, b0, b1;
    #pragma unroll
    for (int r = 0; r < 8; r++) {
      const unsigned v = *(const unsigned*)&t[r * 520 + p * 2];
      a0.s[r] = (unsigned short)(v & 0xffffu);
      b0.s[r] = (unsigned short)(v >> 16);
    }
    #pragma unroll
    for (int r = 0; r < 8; r++) {
      const unsigned v = *(const unsigned*)&t[(r + 8) * 520 + p * 2];
      a1.s[r] = (unsigned short)(v & 0xffffu);
      b1.s[r] = (unsigned short)(v >> 16);
    }
    unsigned short* o0 = xT + (size_t)(2 * p) * 16384 + r0;
    *(uint4*)o0 = a0.u; *(uint4*)(o0 + 8) = a1.u;
    unsigned short* o1 = xT + (size_t)(2 * p + 1) * 16384 + r0;
    *(uint4*)o1 = b0.u; *(uint4*)(o1 + 8) = b1.u;
  }
}

// ---------------- generic u16 transpose: in[R][C] -> out[C][R], 64x64 tiles ----------------
__global__ __launch_bounds__(256) void tr_kernel(const unsigned short* __restrict__ in,
    unsigned short* __restrict__ out, int R, int C) {
  __shared__ __align__(16) unsigned short t[64 * 72];
  const int c0 = blockIdx.x * 64, r0 = blockIdx.y * 64;
  const int tid = threadIdx.x;
  #pragma unroll
  for (int i = 0; i < 2; i++) {
    const int idx = tid + i * 256;
    const int r = idx >> 3, q = idx & 7;
    const uint4 v = *(const uint4*)(in + (size_t)(r0 + r) * C + c0 + q * 8);
    *(uint4*)&t[r * 72 + ((q ^ (r >> 3)) * 8)] = v;
  }
  __syncthreads();
  #pragma unroll
  for (int i = 0; i < 2; i++) {
    const int idx = tid + i * 256;
    const int c = idx >> 3, g = idx & 7;
    union { unsigned short s[8]; uint4 u; } pk;
    #pragma unroll
    for (int j = 0; j < 8; j++)
      pk.s[j] = t[(g * 8 + j) * 72 + (((c >> 3) ^ g) * 8) + (c & 7)];
    *(uint4*)(out + (size_t)(c0 + c) * R + r0 + g * 8) = pk.u;
  }
}

// ---------------- chunked SSM v4: one block per d, internal loop over both batch halves ----------------
// Tables staged once into padded LDS (pitch 68) and reused for h=0,1; carry buffer I
// overwrites E in place (Eb packed bf16 re|im, pitch 131, uniform 2-way banked).
__global__ __launch_bounds__(256, 2) void ssm_kernel(
    const unsigned short* __restrict__ xT,
    const unsigned short* __restrict__ Pre, const unsigned short* __restrict__ Pim,
    const unsigned short* __restrict__ Mre, const unsigned short* __restrict__ Mim,
    const unsigned short* __restrict__ Tt,
    const float* __restrict__ W64r, const float* __restrict__ W64i,
    const float* __restrict__ film, unsigned short* __restrict__ y2) {
  extern __shared__ char smem[];
  unsigned short* Pr = (unsigned short*)smem;                // [64][68]
  unsigned short* Pi = Pr + 64 * 68;
  unsigned short* Mr = Pi + 64 * 68;
  unsigned short* Mi = Mr + 64 * 68;
  unsigned short* Tl = Mi + 64 * 68;
  unsigned int*   Eb = (unsigned int*)(Tl + 64 * 68);        // [64][131] bf16 re|im

  const int d = blockIdx.x;              // 512 blocks
  const int tid = threadIdx.x;
  const int wv = tid >> 6, lane = tid & 63;
  const int n15 = lane & 15, quad = lane >> 4;
  const int j0 = wv * 32;                // local j base (128 j per half)
  const size_t dtab = (size_t)d * 4096;

  // ---- stage tables into LDS (5 x 8KB, pitch 64 -> 68), once for both halves
  {
    const unsigned short* gt[5] = {Pre + dtab, Pim + dtab, Mre + dtab, Mim + dtab, Tt + dtab};
    unsigned short* lt[5] = {Pr, Pi, Mr, Mi, Tl};
    #pragma unroll
    for (int i = 0; i < 10; i++) {
      const int idx = tid + i * 256;
      const int tb = idx >> 9, r = (idx >> 3) & 63, g = idx & 7;
      const uint4 v = *(const uint4*)(gt[tb] + r * 64 + g * 8);
      *(uint4*)&lt[tb][r * 68 + g * 8] = v;
    }
  }
  // X fragments for both halves (B-operand), issued up front for MLP
  bf8v Xf[2][2][2];
  #pragma unroll
  for (int h = 0; h < 2; h++)
    #pragma unroll
    for (int ct = 0; ct < 2; ct++)
      #pragma unroll
      for (int kq = 0; kq < 2; kq++)
        Xf[h][ct][kq] = *(const bf8v*)(xT + (size_t)d * 16384 +
            (h * 128 + j0 + ct * 16 + n15) * 64 + kq * 32 + quad * 8);
  __syncthreads();

  #pragma unroll
  for (int h = 0; h < 2; h++) {
    const int jg0 = h * 128;
    // ---- Phase 1: E = P @ X  (E[n][j])
    {
      f4v Er[4][2], Ei[4][2];
      #pragma unroll
      for (int a = 0; a < 4; a++)
        #pragma unroll
        for (int b2 = 0; b2 < 2; b2++) { Er[a][b2] = (f4v){0,0,0,0}; Ei[a][b2] = (f4v){0,0,0,0}; }
      #pragma unroll
      for (int mt = 0; mt < 4; mt++)
        #pragma unroll
        for (int kq = 0; kq < 2; kq++) {
          const bf8v pr = *(const bf8v*)&Pr[(mt * 16 + n15) * 68 + kq * 32 + quad * 8];
          const bf8v pi = *(const bf8v*)&Pi[(mt * 16 + n15) * 68 + kq * 32 + quad * 8];
          #pragma unroll
          for (int ct = 0; ct < 2; ct++) {
            Er[mt][ct] = __builtin_amdgcn_mfma_f32_16x16x32_bf16(pr, Xf[h][ct][kq], Er[mt][ct], 0, 0, 0);
            Ei[mt][ct] = __builtin_amdgcn_mfma_f32_16x16x32_bf16(pi, Xf[h][ct][kq], Ei[mt][ct], 0, 0, 0);
          }
        }
      #pragma unroll
      for (int mt = 0; mt < 4; mt++)
        #pragma unroll
        for (int ct = 0; ct < 2; ct++)
          #pragma unroll
          for (int i = 0; i < 4; i++) {
            const int row = mt * 16 + quad * 4 + i;
            const int col = j0 + ct * 16 + n15;
            Eb[row * 131 + col] =
                (unsigned)f2bf(Er[mt][ct][i]) | ((unsigned)f2bf(Ei[mt][ct][i]) << 16);
          }
    }
    __syncthreads();

    // ---- Phase 2: per-(n, batch) 32-step carry prefix, in place
    {
      const int n = lane, bp = wv;             // batch = h*4 + bp
      const float wre = W64r[d * 64 + n], wim = W64i[d * 64 + n];
      unsigned int* row = &Eb[n * 131 + bp * 32];
      float str = 0.f, sti = 0.f;
      #pragma unroll
      for (int c = 0; c < 32; c++) {
        const unsigned u = row[c];
        row[c] = (unsigned)f2bf(str) | ((unsigned)f2bf(sti) << 16);
        const float er = bf2f((unsigned short)(u & 0xffffu));
        const float ei = bf2f((unsigned short)(u >> 16));
        const float nr = er + wre * str - wim * sti;
        const float ni = ei + wre * sti + wim * str;
        str = nr; sti = ni;
      }
    }
    __syncthreads();

    // ---- Phase 3: Y = T @ X + Mre @ I_re^T + (-Mim) @ I_im^T
    f4v Y[4][2];
    #pragma unroll
    for (int a = 0; a < 4; a++)
      #pragma unroll
      for (int b2 = 0; b2 < 2; b2++) Y[a][b2] = (f4v){0,0,0,0};

    #pragma unroll
    for (int mt = 0; mt < 4; mt++)
      #pragma unroll
      for (int kq = 0; kq < 2; kq++) {
        const bf8v tf = *(const bf8v*)&Tl[(mt * 16 + n15) * 68 + kq * 32 + quad * 8];
        #pragma unroll
        for (int ct = 0; ct < 2; ct++)
          Y[mt][ct] = __builtin_amdgcn_mfma_f32_16x16x32_bf16(tf, Xf[h][ct][kq], Y[mt][ct], 0, 0, 0);
      }

    #pragma unroll
    for (int kq = 0; kq < 2; kq++) {
      BF8 ir[2], ii[2];
      #pragma unroll
      for (int ct = 0; ct < 2; ct++)
        #pragma unroll
        for (int jj = 0; jj < 8; jj++) {
          const unsigned u = Eb[(kq * 32 + quad * 8 + jj) * 131 + (j0 + ct * 16 + n15)];
          ir[ct].e[jj] = (unsigned short)(u & 0xffffu);
          ii[ct].e[jj] = (unsigned short)(u >> 16);
        }
      #pragma unroll
      for (int mt = 0; mt < 4; mt++) {
        const bf8v mr = *(const bf8v*)&Mr[(mt * 16 + n15) * 68 + kq * 32 + quad * 8];
        const bf8v mi = *(const bf8v*)&Mi[(mt * 16 + n15) * 68 + kq * 32 + quad * 8];
        #pragma unroll
        for (int ct = 0; ct < 2; ct++) {
          Y[mt][ct] = __builtin_amdgcn_mfma_f32_16x16x32_bf16(mr, ir[ct].v, Y[mt][ct], 0, 0, 0);
          Y[mt][ct] = __builtin_amdgcn_mfma_f32_16x16x32_bf16(mi, ii[ct].v, Y[mt][ct], 0, 0, 0);
        }
      }
    }

    // ---- epilogue: FiLM + store y2[d][jglob*64 + t]
    #pragma unroll
    for (int ct = 0; ct < 2; ct++) {
      const int jglob = jg0 + j0 + ct * 16 + n15;
      const int b = jglob >> 5;
      const float scl = 1.f + film[b * 1024 + d];
      const float shf = film[b * 1024 + 512 + d];
      #pragma unroll
      for (int mt = 0; mt < 4; mt++) {
        union { unsigned short s[4]; uint2 u; } pk;
        #pragma unroll
        for (int i = 0; i < 4; i++)
          pk.s[i] = f2bf(fmaf(Y[mt][ct][i], scl, shf));
        *(uint2*)(y2 + (size_t)d * 16384 + jglob * 64 + mt * 16 + quad * 4) = pk.u;
      }
    }
    if (h == 0) __syncthreads();   // Eb reused by next half
  }
}

// ---------------- out_proj + GLU + residual: 256m x 64cpair blocks, BK=64, swizzled ----------------
__global__ __launch_bounds__(256) void gemm_kernel(
    const unsigned short* __restrict__ y2n, const unsigned short* __restrict__ Wb,
    const float* __restrict__ bo, const float* __restrict__ x,
    float* __restrict__ out) {
  __shared__ __align__(16) unsigned short Al[256 * 64];   // 32 KB
  __shared__ __align__(16) unsigned short Bl[128 * 64];   // 16 KB
  const int m0 = blockIdx.x * 256, cp0 = blockIdx.y * 64;
  const int tid = threadIdx.x;
  const int wv = tid >> 6, lane = tid & 63;
  const int n15 = lane & 15, quad = lane >> 4;
  const int lr = lane >> 3;            // 0..7 row-in-group
  const int lg = lane & 7;             // 0..7 k-group
  const int sg = (lg ^ lr) * 8;        // swizzled source k-offset

  f4v acc[4][8];
  #pragma unroll
  for (int mt = 0; mt < 4; mt++)
    #pragma unroll
    for (int t4 = 0; t4 < 8; t4++) acc[mt][t4] = (f4v){0.f, 0.f, 0.f, 0.f};

  for (int kk = 0; kk < 8; kk++) {
    #pragma unroll
    for (int i = 0; i < 8; i++) {     // A: wave stages rows [wv*64, +64)
      const int row = wv * 64 + i * 8 + lr;
      gld16(y2n + (size_t)(m0 + row) * 512 + kk * 64 + sg, Al + (wv * 64 + i * 8) * 64);
    }
    #pragma unroll
    for (int i = 0; i < 4; i++) {     // B: wave stages rows [wv*32, +32)
      const int row = wv * 32 + i * 8 + lr;
      const int cg = (row < 64) ? (cp0 + row) : (512 + cp0 + row - 64);
      gld16(Wb + (size_t)cg * 512 + kk * 64 + sg, Bl + (wv * 32 + i * 8) * 64);
    }
    __syncthreads();
    #pragma unroll
    for (int kq = 0; kq < 2; kq++) {
      bf8v av[4], bv[8];
      #pragma unroll
      for (int mt = 0; mt < 4; mt++) {
        const int row = wv * 64 + mt * 16 + n15;
        av[mt] = *(const bf8v*)&Al[row * 64 + (((kq * 4 + quad) ^ (row & 7)) * 8)];
      }
      #pragma unroll
      for (int t4 = 0; t4 < 8; t4++) {
        const int row = t4 * 16 + n15;
        bv[t4] = *(const bf8v*)&Bl[row * 64 + (((kq * 4 + quad) ^ (row & 7)) * 8)];
      }
      #pragma unroll
      for (int mt = 0; mt < 4; mt++)
        #pragma unroll
        for (int t4 = 0; t4 < 8; t4++)
          acc[mt][t4] = __builtin_amdgcn_mfma_f32_16x16x32_bf16(av[mt], bv[t4], acc[mt][t4], 0, 0, 0);
    }
    __syncthreads();
  }
  #pragma unroll
  for (int mt = 0; mt < 4; mt++) {
    const int mrow = m0 + wv * 64 + mt * 16 + quad * 4;
    #pragma unroll
    for (int t4 = 0; t4 < 4; t4++) {
      const int c = cp0 + t4 * 16 + n15;
      const float ba = bo[c], bg = bo[512 + c];
      #pragma unroll
      for (int i = 0; i < 4; i++) {
        const size_t off = (size_t)(mrow + i) * 512 + c;
        const float av2 = acc[mt][t4][i] + ba;
        const float gv = acc[mt][t4 + 4][i] + bg;
        out[off] = x[off] + av2 * (1.f / (1.f + __expf(-gv)));
      }
    }
  }
}

extern "C" void kernel_launch(void* const* d_in, const int* in_sizes, int n_in,
                              void* d_out, int out_size, void* d_ws, size_t ws_size,
                              hipStream_t stream) {
  const float* x      = (const float*)d_in[0];
  const float* emb    = (const float*)d_in[1];
  const float* A_real = (const float*)d_in[2];
  const float* A_imag = (const float*)d_in[3];
  const float* C      = (const float*)d_in[4];
  const float* log_dt = (const float*)d_in[5];
  const float* B_ssm  = (const float*)d_in[6];
  const float* D_skip = (const float*)d_in[7];
  const float* gamma  = (const float*)d_in[8];
  const float* beta   = (const float*)d_in[9];
  const float* W_out  = (const float*)d_in[10];
  const float* b_out  = (const float*)d_in[11];
  const float* W_film = (const float*)d_in[12];
  const float* b_film = (const float*)d_in[13];
  float* out = (float*)d_out;

  char* ws = (char*)d_ws;
  size_t o = 0;
  float*          film = (float*)(ws + o);          o += 32768;
  unsigned short* xT   = (unsigned short*)(ws + o); o += 16777216;
  unsigned short* Wb   = (unsigned short*)(ws + o); o += 1048576;
  unsigned short* Pre  = (unsigned short*)(ws + o); o += 4194304;
  unsigned short* Pim  = (unsigned short*)(ws + o); o += 4194304;
  unsigned short* Mre  = (unsigned short*)(ws + o); o += 4194304;
  unsigned short* Mim  = (unsigned short*)(ws + o); o += 4194304;
  unsigned short* Tt   = (unsigned short*)(ws + o); o += 4194304;
  float*          W64r = (float*)(ws + o);          o += 131072;
  float*          W64i = (float*)(ws + o);          o += 131072;
  unsigned short* y2   = (unsigned short*)(ws + o); o += 16777216;   // [d][m]
  unsigned short* y2n  = (unsigned short*)(ws + o); o += 16777216;   // [m][d]

  prelude_kernel<<<dim3(4096), dim3(256), 0, stream>>>(
      emb, W_film, b_film, film, W_out, Wb,
      A_real, A_imag, C, log_dt, B_ssm, D_skip,
      Pre, Pim, Mre, Mim, Tt, W64r, W64i,
      x, gamma, beta, xT);
  ssm_kernel<<<dim3(512), dim3(256), 77056, stream>>>(xT, Pre, Pim, Mre, Mim, Tt,
                                                      W64r, W64i, film, y2);
  tr_kernel<<<dim3(256, 8), dim3(256), 0, stream>>>(y2, y2n, 512, 16384);
  gemm_kernel<<<dim3(64, 8), dim3(256), 0, stream>>>(y2n, Wb, b_out, x, out);
}

// Round 7
// 184.506 us; speedup vs baseline: 1.0630x; 1.0630x over previous
//
#include <hip/hip_runtime.h>
#include <math.h>

typedef __attribute__((ext_vector_type(8))) short bf8v;
typedef __attribute__((ext_vector_type(4))) float f4v;

union BF8 { bf8v v; unsigned short e[8]; };
union U4 { uint4 u; unsigned short e[8]; };

__device__ __forceinline__ float bf2f(unsigned short u) {
  union { unsigned int i; float f; } c; c.i = ((unsigned int)u) << 16; return c.f;
}
__device__ __forceinline__ unsigned short f2bf(float f) {
  union { float f; unsigned int i; } c; c.f = f;
  return (unsigned short)((c.i + 0x7fffu + ((c.i >> 16) & 1u)) >> 16);
}
// global -> LDS direct DMA, 16B/lane; LDS dest = wave-uniform base + lane*16
__device__ __forceinline__ void gld16(const unsigned short* g, unsigned short* l) {
  __builtin_amdgcn_global_load_lds(
      (const __attribute__((address_space(1))) unsigned int*)g,
      (__attribute__((address_space(3))) unsigned int*)l, 16, 0, 0);
}

// ---------------- fused prelude + LayerNorm/transpose ----------------
// blk<2048: FiLM; <2560: wcvt; <3072: per-d tables; else LN+transpose (16 rows)
__global__ __launch_bounds__(256) void prelude_kernel(
    const float* __restrict__ emb, const float* __restrict__ Wf,
    const float* __restrict__ bfm, float* __restrict__ film,
    const float* __restrict__ W, unsigned short* __restrict__ Wb,
    const float* __restrict__ A_real, const float* __restrict__ A_imag,
    const float* __restrict__ Cc, const float* __restrict__ log_dt,
    const float* __restrict__ B_ssm, const float* __restrict__ D_skip,
    unsigned short* __restrict__ Pre, unsigned short* __restrict__ Pim,
    unsigned short* __restrict__ Mre, unsigned short* __restrict__ Mim,
    unsigned short* __restrict__ Tt, float* __restrict__ W64r, float* __restrict__ W64i,
    const float* __restrict__ x, const float* __restrict__ gamma,
    const float* __restrict__ beta, unsigned short* __restrict__ xT) {
  __shared__ __align__(16) char sh[16 * 520 * 2];
  const int blk = blockIdx.x;
  const int tid = threadIdx.x;
  if (blk < 2048) {            // ---- FiLM
    const int gw = blk * 4 + (tid >> 6);
    const int lane = tid & 63;
    const int b = gw >> 10, j = gw & 1023;
    const float4* ep = (const float4*)(emb + (size_t)b * 512) + lane * 2;
    const float4* wp = (const float4*)(Wf + (size_t)j * 512) + lane * 2;
    float acc = 0.f;
    #pragma unroll
    for (int i = 0; i < 2; i++) {
      const float4 e = ep[i], w = wp[i];
      acc += (e.x / (1.f + __expf(-e.x))) * w.x;
      acc += (e.y / (1.f + __expf(-e.y))) * w.y;
      acc += (e.z / (1.f + __expf(-e.z))) * w.z;
      acc += (e.w / (1.f + __expf(-e.w))) * w.w;
    }
    #pragma unroll
    for (int off = 32; off >= 1; off >>= 1) acc += __shfl_xor(acc, off);
    if (lane == 0) film[(size_t)b * 1024 + j] = acc + bfm[j];
  } else if (blk < 2560) {     // ---- W_out fp32 -> bf16
    const int i = (blk - 2048) * 256 + tid;
    const float4 v = ((const float4*)W)[i];
    uint2 pk;
    pk.x = (unsigned)f2bf(v.x) | ((unsigned)f2bf(v.y) << 16);
    pk.y = (unsigned)f2bf(v.z) | ((unsigned)f2bf(v.w) << 16);
    ((uint2*)Wb)[i] = pk;
  } else if (blk < 3072) {     // ---- tables for d
    float* Ktl = (float*)sh;
    const int d = blk - 2560;
    const float dt = __expf(log_dt[d]);
    const int wv = tid >> 6, n = tid & 63;
    {  // K[tau] = Re(sum_n cdt_n w_n^tau) (+D_skip at tau=0)
      const int dn = d * 64 + n;
      const float ar = dt * A_real[dn], ai = dt * A_imag[dn];
      const float bs = B_ssm[dn] * dt;
      const float c0 = Cc[dn * 2] * bs, c1 = Cc[dn * 2 + 1] * bs;
      #pragma unroll
      for (int i = 0; i < 16; i++) {
        const float tau = (float)(wv * 16 + i);
        const float ex = __expf(ar * tau);
        float sn, cs; __sincosf(ai * tau, &sn, &cs);
        float r = ex * (c0 * cs - c1 * sn);
        #pragma unroll
        for (int off = 32; off >= 1; off >>= 1) r += __shfl_xor(r, off);
        if (n == 0) Ktl[wv * 16 + i] = (wv * 16 + i == 0) ? (r + D_skip[d]) : r;
      }
    }
    __syncthreads();
    // P[n][s] = w_n^(63-s)
    for (int g = tid; g < 512; g += 256) {
      const int nn = g >> 3, s0 = (g & 7) * 8;
      const int dn = d * 64 + nn;
      const float ar = dt * A_real[dn], ai = dt * A_imag[dn];
      union { unsigned short s[8]; uint4 u; } pr, pi;
      #pragma unroll
      for (int j = 0; j < 8; j++) {
        const float k = (float)(63 - (s0 + j));
        const float ex = __expf(ar * k);
        float sn, cs; __sincosf(ai * k, &sn, &cs);
        pr.s[j] = f2bf(ex * cs); pi.s[j] = f2bf(ex * sn);
      }
      *(uint4*)(Pre + (size_t)d * 4096 + nn * 64 + s0) = pr.u;
      *(uint4*)(Pim + (size_t)d * 4096 + nn * 64 + s0) = pi.u;
    }
    // M[t][n]: re = Re(cdt_n w_n^(t+1)), im = -Im(...)
    for (int g = tid; g < 512; g += 256) {
      const int t = g >> 3, n0 = (g & 7) * 8;
      union { unsigned short s[8]; uint4 u; } mr, mi;
      #pragma unroll
      for (int j = 0; j < 8; j++) {
        const int dn = d * 64 + n0 + j;
        const float ar = dt * A_real[dn], ai = dt * A_imag[dn];
        const float bs = B_ssm[dn] * dt;
        const float c0 = Cc[dn * 2] * bs, c1 = Cc[dn * 2 + 1] * bs;
        const float k = (float)(t + 1);
        const float ex = __expf(ar * k);
        float sn, cs; __sincosf(ai * k, &sn, &cs);
        mr.s[j] = f2bf(ex * (c0 * cs - c1 * sn));
        mi.s[j] = f2bf(-ex * (c0 * sn + c1 * cs));
      }
      *(uint4*)(Mre + (size_t)d * 4096 + t * 64 + n0) = mr.u;
      *(uint4*)(Mim + (size_t)d * 4096 + t * 64 + n0) = mi.u;
    }
    // T[t][s] = K[t-s] for s<=t
    for (int g = tid; g < 512; g += 256) {
      const int t = g >> 3, s0 = (g & 7) * 8;
      union { unsigned short s[8]; uint4 u; } tv;
      #pragma unroll
      for (int j = 0; j < 8; j++) {
        const int s = s0 + j;
        tv.s[j] = (s <= t) ? f2bf(Ktl[t - s]) : (unsigned short)0;
      }
      *(uint4*)(Tt + (size_t)d * 4096 + t * 64 + s0) = tv.u;
    }
    if (tid < 64) {
      const int dn = d * 64 + tid;
      const float ex = __expf(dt * A_real[dn] * 64.f);
      float sn, cs; __sincosf(dt * A_imag[dn] * 64.f, &sn, &cs);
      W64r[d * 64 + tid] = ex * cs;
      W64i[d * 64 + tid] = ex * sn;
    }
  } else {                     // ---- LayerNorm + transpose, rows r0..r0+15
    unsigned short* t = (unsigned short*)sh;
    const int r0 = (blk - 3072) * 16;
    const int wv = tid >> 6, lane = tid & 63;
    const float4* gp = (const float4*)gamma + lane * 2;
    const float4* bp = (const float4*)beta  + lane * 2;
    const float4 g0 = gp[0], g1 = gp[1], bb0 = bp[0], bb1 = bp[1];
    #pragma unroll
    for (int i = 0; i < 4; i++) {
      const int r = wv * 4 + i;
      const float4* xr = (const float4*)(x + (size_t)(r0 + r) * 512) + lane * 2;
      const float4 v0 = xr[0], v1 = xr[1];
      float s  = v0.x + v0.y + v0.z + v0.w + v1.x + v1.y + v1.z + v1.w;
      float sq = v0.x*v0.x + v0.y*v0.y + v0.z*v0.z + v0.w*v0.w
               + v1.x*v1.x + v1.y*v1.y + v1.z*v1.z + v1.w*v1.w;
      #pragma unroll
      for (int off = 32; off >= 1; off >>= 1) {
        s  += __shfl_xor(s, off);
        sq += __shfl_xor(sq, off);
      }
      const float mu   = s * (1.f / 512.f);
      const float var  = sq * (1.f / 512.f) - mu * mu;
      const float rstd = rsqrtf(var + 1e-5f);
      uint4 pk;
      pk.x = (unsigned)f2bf((v0.x - mu) * rstd * g0.x + bb0.x)
           | ((unsigned)f2bf((v0.y - mu) * rstd * g0.y + bb0.y) << 16);
      pk.y = (unsigned)f2bf((v0.z - mu) * rstd * g0.z + bb0.z)
           | ((unsigned)f2bf((v0.w - mu) * rstd * g0.w + bb0.w) << 16);
      pk.z = (unsigned)f2bf((v1.x - mu) * rstd * g1.x + bb1.x)
           | ((unsigned)f2bf((v1.y - mu) * rstd * g1.y + bb1.y) << 16);
      pk.w = (unsigned)f2bf((v1.z - mu) * rstd * g1.z + bb1.z)
           | ((unsigned)f2bf((v1.w - mu) * rstd * g1.w + bb1.w) << 16);
      *(uint4*)&t[r * 520 + lane * 8] = pk;
    }
    __syncthreads();
    const int p = tid;
    union { unsigned short s[8]; uint4 u; } a0, a1, b0, b1;
    #pragma unroll
    for (int r = 0; r < 8; r++) {
      const unsigned v = *(const unsigned*)&t[r * 520 + p * 2];
      a0.s[r] = (unsigned short)(v & 0xffffu);
      b0.s[r] = (unsigned short)(v >> 16);
    }
    #pragma unroll
    for (int r = 0; r < 8; r++) {
      const unsigned v = *(const unsigned*)&t[(r + 8) * 520 + p * 2];
      a1.s[r] = (unsigned short)(v & 0xffffu);
      b1.s[r] = (unsigned short)(v >> 16);
    }
    unsigned short* o0 = xT + (size_t)(2 * p) * 16384 + r0;
    *(uint4*)o0 = a0.u; *(uint4*)(o0 + 8) = a1.u;
    unsigned short* o1 = xT + (size_t)(2 * p + 1) * 16384 + r0;
    *(uint4*)o1 = b0.u; *(uint4*)(o1 + 8) = b1.u;
  }
}

// ---------------- chunked SSM v4: one block per d, internal loop over both batch halves ----------------
__global__ __launch_bounds__(256, 2) void ssm_kernel(
    const unsigned short* __restrict__ xT,
    const unsigned short* __restrict__ Pre, const unsigned short* __restrict__ Pim,
    const unsigned short* __restrict__ Mre, const unsigned short* __restrict__ Mim,
    const unsigned short* __restrict__ Tt,
    const float* __restrict__ W64r, const float* __restrict__ W64i,
    const float* __restrict__ film, unsigned short* __restrict__ y2) {
  extern __shared__ char smem[];
  unsigned short* Pr = (unsigned short*)smem;                // [64][68]
  unsigned short* Pi = Pr + 64 * 68;
  unsigned short* Mr = Pi + 64 * 68;
  unsigned short* Mi = Mr + 64 * 68;
  unsigned short* Tl = Mi + 64 * 68;
  unsigned int*   Eb = (unsigned int*)(Tl + 64 * 68);        // [64][131] bf16 re|im

  const int d = blockIdx.x;              // 512 blocks
  const int tid = threadIdx.x;
  const int wv = tid >> 6, lane = tid & 63;
  const int n15 = lane & 15, quad = lane >> 4;
  const int j0 = wv * 32;
  const size_t dtab = (size_t)d * 4096;

  {  // stage tables into LDS once for both halves
    const unsigned short* gt[5] = {Pre + dtab, Pim + dtab, Mre + dtab, Mim + dtab, Tt + dtab};
    unsigned short* lt[5] = {Pr, Pi, Mr, Mi, Tl};
    #pragma unroll
    for (int i = 0; i < 10; i++) {
      const int idx = tid + i * 256;
      const int tb = idx >> 9, r = (idx >> 3) & 63, g = idx & 7;
      const uint4 v = *(const uint4*)(gt[tb] + r * 64 + g * 8);
      *(uint4*)&lt[tb][r * 68 + g * 8] = v;
    }
  }
  bf8v Xf[2][2][2];
  #pragma unroll
  for (int h = 0; h < 2; h++)
    #pragma unroll
    for (int ct = 0; ct < 2; ct++)
      #pragma unroll
      for (int kq = 0; kq < 2; kq++)
        Xf[h][ct][kq] = *(const bf8v*)(xT + (size_t)d * 16384 +
            (h * 128 + j0 + ct * 16 + n15) * 64 + kq * 32 + quad * 8);
  __syncthreads();

  #pragma unroll
  for (int h = 0; h < 2; h++) {
    const int jg0 = h * 128;
    {  // Phase 1: E = P @ X
      f4v Er[4][2], Ei[4][2];
      #pragma unroll
      for (int a = 0; a < 4; a++)
        #pragma unroll
        for (int b2 = 0; b2 < 2; b2++) { Er[a][b2] = (f4v){0,0,0,0}; Ei[a][b2] = (f4v){0,0,0,0}; }
      #pragma unroll
      for (int mt = 0; mt < 4; mt++)
        #pragma unroll
        for (int kq = 0; kq < 2; kq++) {
          const bf8v pr = *(const bf8v*)&Pr[(mt * 16 + n15) * 68 + kq * 32 + quad * 8];
          const bf8v pi = *(const bf8v*)&Pi[(mt * 16 + n15) * 68 + kq * 32 + quad * 8];
          #pragma unroll
          for (int ct = 0; ct < 2; ct++) {
            Er[mt][ct] = __builtin_amdgcn_mfma_f32_16x16x32_bf16(pr, Xf[h][ct][kq], Er[mt][ct], 0, 0, 0);
            Ei[mt][ct] = __builtin_amdgcn_mfma_f32_16x16x32_bf16(pi, Xf[h][ct][kq], Ei[mt][ct], 0, 0, 0);
          }
        }
      #pragma unroll
      for (int mt = 0; mt < 4; mt++)
        #pragma unroll
        for (int ct = 0; ct < 2; ct++)
          #pragma unroll
          for (int i = 0; i < 4; i++) {
            const int row = mt * 16 + quad * 4 + i;
            const int col = j0 + ct * 16 + n15;
            Eb[row * 131 + col] =
                (unsigned)f2bf(Er[mt][ct][i]) | ((unsigned)f2bf(Ei[mt][ct][i]) << 16);
          }
    }
    __syncthreads();

    {  // Phase 2: carry prefix in place
      const int n = lane, bp = wv;
      const float wre = W64r[d * 64 + n], wim = W64i[d * 64 + n];
      unsigned int* row = &Eb[n * 131 + bp * 32];
      float str = 0.f, sti = 0.f;
      #pragma unroll
      for (int c = 0; c < 32; c++) {
        const unsigned u = row[c];
        row[c] = (unsigned)f2bf(str) | ((unsigned)f2bf(sti) << 16);
        const float er = bf2f((unsigned short)(u & 0xffffu));
        const float ei = bf2f((unsigned short)(u >> 16));
        const float nr = er + wre * str - wim * sti;
        const float ni = ei + wre * sti + wim * str;
        str = nr; sti = ni;
      }
    }
    __syncthreads();

    // Phase 3: Y = T @ X + Mre @ I_re^T + (-Mim) @ I_im^T
    f4v Y[4][2];
    #pragma unroll
    for (int a = 0; a < 4; a++)
      #pragma unroll
      for (int b2 = 0; b2 < 2; b2++) Y[a][b2] = (f4v){0,0,0,0};

    #pragma unroll
    for (int mt = 0; mt < 4; mt++)
      #pragma unroll
      for (int kq = 0; kq < 2; kq++) {
        const bf8v tf = *(const bf8v*)&Tl[(mt * 16 + n15) * 68 + kq * 32 + quad * 8];
        #pragma unroll
        for (int ct = 0; ct < 2; ct++)
          Y[mt][ct] = __builtin_amdgcn_mfma_f32_16x16x32_bf16(tf, Xf[h][ct][kq], Y[mt][ct], 0, 0, 0);
      }

    #pragma unroll
    for (int kq = 0; kq < 2; kq++) {
      BF8 ir[2], ii[2];
      #pragma unroll
      for (int ct = 0; ct < 2; ct++)
        #pragma unroll
        for (int jj = 0; jj < 8; jj++) {
          const unsigned u = Eb[(kq * 32 + quad * 8 + jj) * 131 + (j0 + ct * 16 + n15)];
          ir[ct].e[jj] = (unsigned short)(u & 0xffffu);
          ii[ct].e[jj] = (unsigned short)(u >> 16);
        }
      #pragma unroll
      for (int mt = 0; mt < 4; mt++) {
        const bf8v mr = *(const bf8v*)&Mr[(mt * 16 + n15) * 68 + kq * 32 + quad * 8];
        const bf8v mi = *(const bf8v*)&Mi[(mt * 16 + n15) * 68 + kq * 32 + quad * 8];
        #pragma unroll
        for (int ct = 0; ct < 2; ct++) {
          Y[mt][ct] = __builtin_amdgcn_mfma_f32_16x16x32_bf16(mr, ir[ct].v, Y[mt][ct], 0, 0, 0);
          Y[mt][ct] = __builtin_amdgcn_mfma_f32_16x16x32_bf16(mi, ii[ct].v, Y[mt][ct], 0, 0, 0);
        }
      }
    }

    #pragma unroll
    for (int ct = 0; ct < 2; ct++) {
      const int jglob = jg0 + j0 + ct * 16 + n15;
      const int b = jglob >> 5;
      const float scl = 1.f + film[b * 1024 + d];
      const float shf = film[b * 1024 + 512 + d];
      #pragma unroll
      for (int mt = 0; mt < 4; mt++) {
        union { unsigned short s[4]; uint2 u; } pk;
        #pragma unroll
        for (int i = 0; i < 4; i++)
          pk.s[i] = f2bf(fmaf(Y[mt][ct][i], scl, shf));
        *(uint2*)(y2 + (size_t)d * 16384 + jglob * 64 + mt * 16 + quad * 4) = pk.u;
      }
    }
    if (h == 0) __syncthreads();
  }
}

// ---------------- out_proj + GLU + residual: 128m x 64cp, BK=64, fused A-transpose ----------------
// A read directly from y2 [d][m]; 4kx8m register transpose; LDS swizzle g ^ (m&7) ^ ((m>>3)&7)
// keeps both write and read phases <=2-way banked. B staged via gld16 with R6's validated swizzle.
__global__ __launch_bounds__(256, 3) void gemm_kernel(
    const unsigned short* __restrict__ y2, const unsigned short* __restrict__ Wb,
    const float* __restrict__ bo, const float* __restrict__ x,
    float* __restrict__ out) {
  __shared__ __align__(16) unsigned short Al[128 * 64];   // 16 KB
  __shared__ __align__(16) unsigned short Bl[128 * 64];   // 16 KB
  const int m0 = blockIdx.x * 128, cp0 = blockIdx.y * 64;
  const int tid = threadIdx.x;
  const int wv = tid >> 6, lane = tid & 63;
  const int n15 = lane & 15, quad = lane >> 4;
  const int lr = lane >> 3;            // 0..7 row-in-group (B staging)
  const int lg = lane & 7;             // 0..7 k-group (B staging)
  const int sg = (lg ^ lr) * 8;        // B: swizzled source k-offset
  const int mg = tid & 15;             // A: m-group (8 m)
  const int kg = tid >> 4;             // A: k-quad group (4 k)

  f4v acc[2][8];
  #pragma unroll
  for (int mi = 0; mi < 2; mi++)
    #pragma unroll
    for (int t4 = 0; t4 < 8; t4++) acc[mi][t4] = (f4v){0.f, 0.f, 0.f, 0.f};

  for (int kk = 0; kk < 8; kk++) {
    // ---- A: load 4 d-rows x 8 m from y2 [d][m], transpose in regs, swizzled LDS store
    U4 q[4];
    #pragma unroll
    for (int r = 0; r < 4; r++)
      q[r].u = *(const uint4*)(y2 + (size_t)(kk * 64 + kg * 4 + r) * 16384 + m0 + mg * 8);
    // ---- B: gld16 rows [wv*32, +32) of the 128 c-rows
    #pragma unroll
    for (int i = 0; i < 4; i++) {
      const int row = wv * 32 + i * 8 + lr;
      const int cg = (row < 64) ? (cp0 + row) : (512 + cp0 + row - 64);
      gld16(Wb + (size_t)cg * 512 + kk * 64 + sg, Bl + (wv * 32 + i * 8) * 64);
    }
    #pragma unroll
    for (int i = 0; i < 8; i++) {
      const int m = mg * 8 + i;
      union { unsigned short e[4]; uint2 u; } o;
      o.e[0] = q[0].e[i]; o.e[1] = q[1].e[i]; o.e[2] = q[2].e[i]; o.e[3] = q[3].e[i];
      *(uint2*)&Al[m * 64 + (((kg >> 1) ^ i ^ (mg & 7)) & 7) * 8 + (kg & 1) * 4] = o.u;
    }
    __syncthreads();
    #pragma unroll
    for (int kq = 0; kq < 2; kq++) {
      bf8v av[2], bv[8];
      #pragma unroll
      for (int mt = 0; mt < 2; mt++) {
        const int row = wv * 32 + mt * 16 + n15;
        const int g = kq * 4 + quad;
        av[mt] = *(const bf8v*)&Al[row * 64 + (((g ^ (row & 7) ^ ((row >> 3) & 7)) & 7) * 8)];
      }
      #pragma unroll
      for (int t4 = 0; t4 < 8; t4++) {
        const int row = t4 * 16 + n15;
        bv[t4] = *(const bf8v*)&Bl[row * 64 + (((kq * 4 + quad) ^ (row & 7)) * 8)];
      }
      #pragma unroll
      for (int mt = 0; mt < 2; mt++)
        #pragma unroll
        for (int t4 = 0; t4 < 8; t4++)
          acc[mt][t4] = __builtin_amdgcn_mfma_f32_16x16x32_bf16(av[mt], bv[t4], acc[mt][t4], 0, 0, 0);
    }
    __syncthreads();
  }
  #pragma unroll
  for (int mt = 0; mt < 2; mt++) {
    const int mrow = m0 + wv * 32 + mt * 16 + quad * 4;
    #pragma unroll
    for (int t4 = 0; t4 < 4; t4++) {
      const int c = cp0 + t4 * 16 + n15;
      const float ba = bo[c], bg = bo[512 + c];
      #pragma unroll
      for (int i = 0; i < 4; i++) {
        const size_t off = (size_t)(mrow + i) * 512 + c;
        const float av2 = acc[mt][t4][i] + ba;
        const float gv = acc[mt][t4 + 4][i] + bg;
        out[off] = x[off] + av2 * (1.f / (1.f + __expf(-gv)));
      }
    }
  }
}

extern "C" void kernel_launch(void* const* d_in, const int* in_sizes, int n_in,
                              void* d_out, int out_size, void* d_ws, size_t ws_size,
                              hipStream_t stream) {
  const float* x      = (const float*)d_in[0];
  const float* emb    = (const float*)d_in[1];
  const float* A_real = (const float*)d_in[2];
  const float* A_imag = (const float*)d_in[3];
  const float* C      = (const float*)d_in[4];
  const float* log_dt = (const float*)d_in[5];
  const float* B_ssm  = (const float*)d_in[6];
  const float* D_skip = (const float*)d_in[7];
  const float* gamma  = (const float*)d_in[8];
  const float* beta   = (const float*)d_in[9];
  const float* W_out  = (const float*)d_in[10];
  const float* b_out  = (const float*)d_in[11];
  const float* W_film = (const float*)d_in[12];
  const float* b_film = (const float*)d_in[13];
  float* out = (float*)d_out;

  char* ws = (char*)d_ws;
  size_t o = 0;
  float*          film = (float*)(ws + o);          o += 32768;
  unsigned short* xT   = (unsigned short*)(ws + o); o += 16777216;
  unsigned short* Wb   = (unsigned short*)(ws + o); o += 1048576;
  unsigned short* Pre  = (unsigned short*)(ws + o); o += 4194304;
  unsigned short* Pim  = (unsigned short*)(ws + o); o += 4194304;
  unsigned short* Mre  = (unsigned short*)(ws + o); o += 4194304;
  unsigned short* Mim  = (unsigned short*)(ws + o); o += 4194304;
  unsigned short* Tt   = (unsigned short*)(ws + o); o += 4194304;
  float*          W64r = (float*)(ws + o);          o += 131072;
  float*          W64i = (float*)(ws + o);          o += 131072;
  unsigned short* y2   = (unsigned short*)(ws + o); o += 16777216;   // [d][m]

  prelude_kernel<<<dim3(4096), dim3(256), 0, stream>>>(
      emb, W_film, b_film, film, W_out, Wb,
      A_real, A_imag, C, log_dt, B_ssm, D_skip,
      Pre, Pim, Mre, Mim, Tt, W64r, W64i,
      x, gamma, beta, xT);
  ssm_kernel<<<dim3(512), dim3(256), 77056, stream>>>(xT, Pre, Pim, Mre, Mim, Tt,
                                                      W64r, W64i, film, y2);
  gemm_kernel<<<dim3(128, 8), dim3(256), 0, stream>>>(y2, Wb, b_out, x, out);
}